// Round 1
// baseline (231.683 us; speedup 1.0000x reference)
//
#include <hip/hip_runtime.h>

// SE(2) depthwise group convolution, fp32.
// out[b,c,t,y,x] = sum_{o,dy,dx} W[c,t,o,dy,dx] * x[b,c,o,y+dy-2,x+dx-2]
// W[c,t,o,dy,dx] = mask(t,dy,dx) * kernel[c,(o-t)%8, iy(t,dy,dx), ix(t,dy,dx)]
//
// B=8 C=32 Or=8 H=W=128, kOr=8 kH=kW=5.

#define TW 32
#define TH 32
#define LW 36              // TW/TH + 4 halo
#define PLANE (LW * LW)    // 1296 floats per orientation plane

__global__ __launch_bounds__(256)
void se2_dwconv(const float* __restrict__ x, const float* __restrict__ kern,
                float* __restrict__ out) {
    __shared__ float ldsx[8 * PLANE];   // 41472 B: 8 input planes with halo
    __shared__ float ldsw[8 * 8 * 25];  // 6400 B: W[t][o][dy*5+dx] for this c

    const int bid = blockIdx.x;
    const int tx = bid & 3;
    const int ty = (bid >> 2) & 3;
    const int bc = bid >> 4;           // b*32 + c
    const int c  = bc & 31;
    const int b  = bc >> 5;
    const int X0 = tx * TW;
    const int Y0 = ty * TH;
    const int tid = threadIdx.x;

    // ---- build rotated weights for this channel: 1600 values ----
    for (int e = tid; e < 1600; e += 256) {
        int t   = e / 200;
        int rem = e - t * 200;
        int o   = rem / 25;
        int k   = rem - o * 25;
        int dy  = k / 5;
        int dx  = k - dy * 5;
        int tp  = (o - t) & 7;
        // match jnp: ang = f32(2*pi) * t / 8 in fp32
        float ang = 6.2831855f * (float)t / 8.0f;
        float ca = cosf(ang), sa = sinf(ang);
        float xx = (float)dx - 2.0f;
        float yy = (float)dy - 2.0f;
        float ysf = sa * xx + ca * yy + 2.0f;
        float xsf = ca * xx - sa * yy + 2.0f;
        int iy = (int)rintf(ysf);   // round-nearest-even == jnp.round
        int ix = (int)rintf(xsf);
        float w = 0.0f;
        if (iy >= 0 && iy < 5 && ix >= 0 && ix < 5)
            w = kern[((c * 8 + tp) * 5 + iy) * 5 + ix];
        ldsw[e] = w;
    }

    // ---- stage 8 input planes (36x36 each, zero-padded halo) ----
    const float* xbase = x + (size_t)(b * 32 + c) * 8 * 16384;
    for (int e = tid; e < 8 * PLANE; e += 256) {
        int o   = e / PLANE;
        int rem = e - o * PLANE;
        int r   = rem / LW;
        int col = rem - r * LW;
        int gy = Y0 - 2 + r;
        int gx = X0 - 2 + col;
        float v = 0.0f;
        if (gy >= 0 && gy < 128 && gx >= 0 && gx < 128)
            v = xbase[o * 16384 + gy * 128 + gx];
        ldsx[e] = v;
    }
    __syncthreads();

    // ---- compute: thread = (t, x-pair, y-half) ----
    const int xp = tid & 15;          // 16 x-pairs -> 32 columns
    const int t  = (tid >> 4) & 7;    // orientation
    const int ys = tid >> 7;          // 0..1
    const int x0 = xp * 2;
    const int y0 = ys * 16;

    float acc[32];
#pragma unroll
    for (int i = 0; i < 32; ++i) acc[i] = 0.0f;

    for (int o = 0; o < 8; ++o) {
        float w[25];
#pragma unroll
        for (int i = 0; i < 25; ++i) w[i] = ldsw[(t * 8 + o) * 25 + i];
        const float* px = &ldsx[o * PLANE];
#pragma unroll
        for (int rr = 0; rr < 20; ++rr) {
            float v[6];
#pragma unroll
            for (int j = 0; j < 6; ++j) v[j] = px[(y0 + rr) * LW + x0 + j];
#pragma unroll
            for (int dy = 0; dy < 5; ++dy) {
                const int yrel = rr - dy;           // compile-time after unroll
                if (yrel >= 0 && yrel < 16) {
#pragma unroll
                    for (int dx = 0; dx < 5; ++dx) {
                        acc[yrel * 2 + 0] += w[dy * 5 + dx] * v[dx];
                        acc[yrel * 2 + 1] += w[dy * 5 + dx] * v[dx + 1];
                    }
                }
            }
        }
    }

    // ---- write 16 rows x 2 cols as float2 ----
    const size_t obase = ((size_t)(b * 32 + c) * 8 + t) * 16384;
#pragma unroll
    for (int y = 0; y < 16; ++y) {
        size_t off = obase + (size_t)(Y0 + y0 + y) * 128 + (X0 + x0);
        *reinterpret_cast<float2*>(out + off) = make_float2(acc[y * 2], acc[y * 2 + 1]);
    }
}

extern "C" void kernel_launch(void* const* d_in, const int* in_sizes, int n_in,
                              void* d_out, int out_size, void* d_ws, size_t ws_size,
                              hipStream_t stream) {
    const float* x    = (const float*)d_in[0];
    const float* kern = (const float*)d_in[1];
    float* out = (float*)d_out;
    // grid: 8 b * 32 c * 4 ty * 4 tx = 4096 blocks
    dim3 grid(4096), block(256);
    se2_dwconv<<<grid, block, 0, stream>>>(x, kern, out);
}